// Round 12
// baseline (126.192 us; speedup 1.0000x reference)
//
#include <hip/hip_runtime.h>
#include <hip/hip_bf16.h>

#define B_ 32
#define D_ 512
#define K_ 64
#define N_ 4096
#define NBLK 256   // grid = 8 x 32, 1 block/CU -> all blocks resident (spin-barrier safe)

typedef __attribute__((ext_vector_type(8))) short short8;   // 8 bf16 (4 VGPRs)
typedef __attribute__((ext_vector_type(4))) short short4v;  // 4 bf16 (8 bytes)
typedef __attribute__((ext_vector_type(4))) float f32x4;

static __device__ __forceinline__ unsigned short f2bf(float f) {
    __hip_bfloat16 h = __float2bfloat16(f);
    return *reinterpret_cast<unsigned short*>(&h);
}
static __device__ __forceinline__ float bf2f(unsigned short u) {
    return __uint_as_float(((unsigned)u) << 16);
}

// LDS carve (bytes): WL 64K | XL 64K | XT 2x8K | PT 8K | sxc 1K
#define SMEM_BYTES 156672
#define WL_OFF 0
#define XL_OFF 65536
#define XT_OFF 131072
#define PT_OFF 147456
#define SXC_OFF 155648

// Device-scope grid barrier: valid ONLY because all NBLK blocks are resident
// (1 block/CU, grid == CU count). cnt is zeroed per launch by a captured
// hipMemsetAsync. atomicAdd RMWs are device-scope coherent across XCDs (m20).
static __device__ __forceinline__ void gridbar(unsigned* cnt) {
    __syncthreads();
    if (threadIdx.x == 0) {
        __threadfence();                    // flush this block's global stores
        atomicAdd(cnt, 1u);
        while (atomicAdd(cnt, 0u) < (unsigned)NBLK) {}
        __threadfence();                    // acquire other blocks' stores
    }
    __syncthreads();
}

// ---------------------------------------------------------------------------
// Single fused kernel: [scores MFMA -> softmax -> P in LDS -> agg MFMA] per
// n-tile (X read from HBM exactly once, P never global), then grid-barrier,
// then the full normalization pipeline with per-block v values held in
// REGISTERS across the barrier (no aggsum round-trip, no extra launches).
// Block 512 thr (8 waves), 1 block/CU. Grid 8 ns x 32 b = 256 blocks.
// ---------------------------------------------------------------------------
__global__ __launch_bounds__(512, 2) void vlad_fused(const float* __restrict__ X,
                                                     const float* __restrict__ W,
                                                     const float* __restrict__ bias,
                                                     const float* __restrict__ centers,
                                                     float* __restrict__ aggs,
                                                     float* __restrict__ ssp,
                                                     float* __restrict__ nrmp,
                                                     float* __restrict__ out,
                                                     unsigned* __restrict__ cnt) {
    extern __shared__ char smem[];
    char* WLp = smem + WL_OFF;
    char* XLp = smem + XL_OFF;
    char* XTp = smem + XT_OFF;
    char* PTp = smem + PT_OFF;
    float2* sxc = (float2*)(smem + SXC_OFF);   // [8 waves][16 lr] (c, sum)

    const int ns = blockIdx.x;   // 0..7  (n-range [ns*512, ns*512+512))
    const int b  = blockIdx.y;
    const int t  = threadIdx.x;
    const int w  = t >> 6;
    const int l  = t & 63;
    const int lg = l >> 4;
    const int lr = l & 15;
    const int strip = w & 3;
    const int khalf = w >> 2;

    // staging role: 2 d-rows x 4 n-cols per thread
    const int dq2 = t >> 4;   // 0..31 -> local d0 = dq2*2
    const int nq  = t & 15;   // n0 = nq*4
    const float* Xbase = X + (size_t)b * D_ * N_ + ns * 512 + nq * 4;

    // ---- prefetch slots: stages 0..3 of tile 0 (slot = stage&3, static idx)
    float4 Sa[4], Sb[4];
#pragma unroll
    for (int s = 0; s < 4; ++s) {
        const float* Xs = Xbase + (size_t)(s * 64 + dq2 * 2) * N_;
        Sa[s] = *(const float4*)&Xs[0];
        Sb[s] = *(const float4*)&Xs[N_];
    }

    // ---- stage full W -> WL [64 k][512 d] bf16, 1KB rows, XOR-swz (validated)
#pragma unroll 4
    for (int j = 0; j < 16; ++j) {
        const int idx = t + j * 512;       // f4 index over [64 k][128 f4]
        const int k = idx >> 7;
        const int cf = idx & 127;
        const float4 wv = *(const float4*)&W[k * D_ + cf * 4];
        const int C = cf >> 1;
        const int swz = (C & ~7) | ((C ^ k) & 7);
        short4v pk;
        pk[0] = (short)f2bf(wv.x); pk[1] = (short)f2bf(wv.y);
        pk[2] = (short)f2bf(wv.z); pk[3] = (short)f2bf(wv.w);
        *(short4v*)(WLp + k * 1024 + (swz << 4) + (cf & 1) * 8) = pk;
    }

    float bias_r[2][4];
#pragma unroll
    for (int ktl = 0; ktl < 2; ++ktl)
#pragma unroll
        for (int r = 0; r < 4; ++r)
            bias_r[ktl][r] = bias[khalf * 32 + ktl * 16 + lg * 4 + r];

    f32x4 aacc[4][4];
#pragma unroll
    for (int m = 0; m < 4; ++m)
#pragma unroll
        for (int kt = 0; kt < 4; ++kt) {
            aacc[m][kt][0] = 0.f; aacc[m][kt][1] = 0.f;
            aacc[m][kt][2] = 0.f; aacc[m][kt][3] = 0.f;
        }
    float ssr[2][4];   // in-register softsum partials (this lane's 8 k's)
#pragma unroll
    for (int ktl = 0; ktl < 2; ++ktl)
#pragma unroll
        for (int r = 0; r < 4; ++r) ssr[ktl][r] = 0.f;

    // staged 2x4 block -> XL + XT[buf]; SINGLE conversion per element (8 f2bf)
    auto stage_write = [&](int buf, int dglob0, const float4& r0, const float4& r1) {
        const unsigned short a0 = f2bf(r0.x), a1 = f2bf(r0.y), a2 = f2bf(r0.z), a3 = f2bf(r0.w);
        const unsigned short b0 = f2bf(r1.x), b1 = f2bf(r1.y), b2 = f2bf(r1.z), b3 = f2bf(r1.w);
        // XL rows dglob0 / dglob0+1 (n-packed)
        {
            const int d = dglob0;
            *(uint2*)(XLp + d * 128 + ((((nq >> 1) ^ d) & 7) << 4) + (nq & 1) * 8) =
                make_uint2((unsigned)a0 | ((unsigned)a1 << 16), (unsigned)a2 | ((unsigned)a3 << 16));
        }
        {
            const int d = dglob0 + 1;
            *(uint2*)(XLp + d * 128 + ((((nq >> 1) ^ d) & 7) << 4) + (nq & 1) * 8) =
                make_uint2((unsigned)b0 | ((unsigned)b1 << 16), (unsigned)b2 | ((unsigned)b3 << 16));
        }
        // XT (d-pair packed), conflict-free swizzle
        const int C = dq2 >> 2;
        const unsigned xv[4] = {(unsigned)a0 | ((unsigned)b0 << 16), (unsigned)a1 | ((unsigned)b1 << 16),
                                (unsigned)a2 | ((unsigned)b2 << 16), (unsigned)a3 | ((unsigned)b3 << 16)};
#pragma unroll
        for (int c = 0; c < 4; ++c) {
            const int n = nq * 4 + c;
            const int sw = (C ^ (n & 7) ^ ((n >> 3) & 7)) & 7;
            *(unsigned*)(XTp + buf * 8192 + n * 128 + (sw << 4) + (dq2 & 3) * 4) = xv[c];
        }
    };

    __syncthreads();   // WL ready

    for (int nt = 0; nt < 8; ++nt) {
        const int base = nt * 8;

        // ---- tile prologue: write stage base (slot 0); refill slot0 <- base+4
        stage_write(0, 0 * 64 + dq2 * 2, Sa[0], Sb[0]);
        {
            const int s4 = base + 4;
            if (s4 < 64) {
                const int nt2 = s4 >> 3, d2 = s4 & 7;
                const float* Xs = Xbase + nt2 * 64 + (size_t)(d2 * 64 + dq2 * 2) * N_;
                Sa[0] = *(const float4*)&Xs[0];
                Sb[0] = *(const float4*)&Xs[N_];
            }
        }
        __syncthreads();

        f32x4 sacc[2];
#pragma unroll
        for (int ktl = 0; ktl < 2; ++ktl) {
            sacc[ktl][0] = 0.f; sacc[ktl][1] = 0.f; sacc[ktl][2] = 0.f; sacc[ktl][3] = 0.f;
        }

#pragma unroll
        for (int dsl = 0; dsl < 8; ++dsl) {
            const int cur = dsl & 1;
            if (dsl < 7) {
                const int slot = (dsl + 1) & 3;
                stage_write(cur ^ 1, (dsl + 1) * 64 + dq2 * 2, Sa[slot], Sb[slot]);
                const int s5 = base + dsl + 5;
                if (s5 < 64) {
                    const int nt2 = s5 >> 3, d2 = s5 & 7;
                    const float* Xs = Xbase + nt2 * 64 + (size_t)(d2 * 64 + dq2 * 2) * N_;
                    Sa[slot] = *(const float4*)&Xs[0];
                    Sb[slot] = *(const float4*)&Xs[N_];
                }
            }
            // MFMA scores stage dsl on XT buf[cur]
            const int n = strip * 16 + lr;
            __builtin_amdgcn_s_setprio(1);
#pragma unroll
            for (int kc = 0; kc < 2; ++kc) {
                const int bC = kc * 4 + lg;
                const int sw = (bC ^ (n & 7) ^ ((n >> 3) & 7)) & 7;
                const short8 bfrag = *(const short8*)(XTp + cur * 8192 + n * 128 + (sw << 4));
#pragma unroll
                for (int ktl = 0; ktl < 2; ++ktl) {
                    const int k = khalf * 32 + ktl * 16 + lr;
                    const int aC = dsl * 8 + kc * 4 + lg;
                    const int swz = (aC & ~7) | ((aC ^ k) & 7);
                    const short8 afrag = *(const short8*)(WLp + k * 1024 + (swz << 4));
                    sacc[ktl] = __builtin_amdgcn_mfma_f32_16x16x32_bf16(afrag, bfrag, sacc[ktl], 0, 0, 0);
                }
            }
            __builtin_amdgcn_s_setprio(0);
            if (dsl < 7) __syncthreads();
        }

        // ---- softmax over k: wave-local shift (exact), single (c,sum) exchange
        float p[2][4];
        float cw = -1e30f;
#pragma unroll
        for (int ktl = 0; ktl < 2; ++ktl)
#pragma unroll
            for (int r = 0; r < 4; ++r) {
                p[ktl][r] = sacc[ktl][r] + bias_r[ktl][r];
                cw = fmaxf(cw, p[ktl][r]);
            }
        cw = fmaxf(cw, __shfl_xor(cw, 16));
        cw = fmaxf(cw, __shfl_xor(cw, 32));
        float sum = 0.f;
#pragma unroll
        for (int ktl = 0; ktl < 2; ++ktl)
#pragma unroll
            for (int r = 0; r < 4; ++r) { p[ktl][r] = __expf(p[ktl][r] - cw); sum += p[ktl][r]; }
        sum += __shfl_xor(sum, 16);
        sum += __shfl_xor(sum, 32);
        if (l < 16) sxc[w * 16 + lr] = make_float2(cw, sum);
        __syncthreads();
        const float2 other = sxc[(w ^ 4) * 16 + lr];
        const float cstar = fmaxf(cw, other.x);
        const float e_own = __expf(cw - cstar);
        const float e_oth = __expf(other.x - cstar);
        const float scale = e_own / (sum * e_own + other.y * e_oth);

        // ---- P tile -> LDS [64 k][64 n] bf16 + in-register softsum partial
        {
            const int n = strip * 16 + lr;
#pragma unroll
            for (int ktl = 0; ktl < 2; ++ktl)
#pragma unroll
                for (int r = 0; r < 4; ++r) {
                    const int k = khalf * 32 + ktl * 16 + lg * 4 + r;
                    const unsigned short us = f2bf(p[ktl][r] * scale);
                    *(unsigned short*)(PTp + k * 128 + ((((n >> 3) ^ k) & 7) << 4) + (n & 7) * 2) = us;
                    ssr[ktl][r] += bf2f(us);
                }
        }
        __syncthreads();

        // ---- agg MFMA: contraction n=64 (2 steps); B-frags hoisted per kc
        __builtin_amdgcn_s_setprio(1);
#pragma unroll
        for (int kc = 0; kc < 2; ++kc) {
            const int aC = kc * 4 + lg;
            short8 bfr[4];
#pragma unroll
            for (int kt = 0; kt < 4; ++kt) {
                const int kk2 = kt * 16 + lr;
                bfr[kt] = *(const short8*)(PTp + kk2 * 128 + (((aC ^ kk2) & 7) << 4));
            }
#pragma unroll
            for (int m = 0; m < 4; ++m) {
                const int d = w * 64 + m * 16 + lr;
                const short8 afrag = *(const short8*)(XLp + d * 128 + (((aC ^ d) & 7) << 4));
#pragma unroll
                for (int kt = 0; kt < 4; ++kt)
                    aacc[m][kt] = __builtin_amdgcn_mfma_f32_16x16x32_bf16(afrag, bfr[kt], aacc[m][kt], 0, 0, 0);
            }
        }
        __builtin_amdgcn_s_setprio(0);
        __syncthreads();   // XL/PT reads done before next tile's prologue write
    }

    // ---- store agg partial: aggs[ns][b][d][k]
    float* ag = aggs + ((size_t)ns * B_ + b) * (D_ * K_);
#pragma unroll
    for (int m = 0; m < 4; ++m)
#pragma unroll
        for (int kt = 0; kt < 4; ++kt)
#pragma unroll
            for (int r = 0; r < 4; ++r)
                ag[(size_t)(w * 64 + m * 16 + lg * 4 + r) * K_ + kt * 16 + lr] = aacc[m][kt][r];

    // ---- softsum partials: butterfly over the 16-lane lr group
#pragma unroll
    for (int ktl = 0; ktl < 2; ++ktl)
#pragma unroll
        for (int r = 0; r < 4; ++r) {
            float v = ssr[ktl][r];
            v += __shfl_xor(v, 1);
            v += __shfl_xor(v, 2);
            v += __shfl_xor(v, 4);
            v += __shfl_xor(v, 8);
            ssr[ktl][r] = v;
        }
    if (lr == 0) {
#pragma unroll
        for (int ktl = 0; ktl < 2; ++ktl)
#pragma unroll
            for (int r = 0; r < 4; ++r) {
                const int k = khalf * 32 + ktl * 16 + lg * 4 + r;
                ssp[(((size_t)b * 8 + ns) * 4 + strip) * K_ + k] = ssr[ktl][r];
            }
    }

    // ================= grid barrier 1: aggs + ssp globally visible ==========
    gridbar(cnt + 0);

    // ---- norm phase 1 (block (ds=ns, b)): ssum, v (kept in regs), sumsq
    const int ds = ns;
    const int k  = t & 63;
    const int dg = t >> 6;            // 0..7
    float* red8  = (float*)smem;      // [8][64]
    float* inv1s = (float*)(smem + 2048);
    float* col2  = (float*)(smem + 2304);
    float* inv2p = (float*)(smem + 2560);

    float s0 = 0.f;
#pragma unroll
    for (int j = 0; j < 4; ++j)
        s0 += ssp[((size_t)b * 32 + dg * 4 + j) * K_ + k];
    red8[dg * 64 + k] = s0;
    __syncthreads();
    float s = 0.f;
#pragma unroll
    for (int j = 0; j < 8; ++j) s += red8[j * 64 + k];
    __syncthreads();

    float vreg[8];
    float sq = 0.f;
#pragma unroll
    for (int j = 0; j < 8; ++j) {
        const int d = ds * 64 + dg + j * 8;
        float v = -centers[d * K_ + k] * s;
#pragma unroll
        for (int i = 0; i < 8; ++i)
            v += aggs[((size_t)i * B_ + b) * (D_ * K_) + (size_t)d * K_ + k];
        vreg[j] = v;
        sq = fmaf(v, v, sq);
    }
    red8[dg * 64 + k] = sq;
    __syncthreads();
    if (t < 64) {
        float tt = 0.f;
#pragma unroll
        for (int j = 0; j < 8; ++j) tt += red8[j * 64 + k];
        nrmp[((size_t)b * 8 + ds) * K_ + k] = tt;
    }

    // ================= grid barrier 2: nrmp globally visible ================
    gridbar(cnt + 16);

    // ---- norm phase 2: finalize norms, scale v (still in registers) -> out
    if (t < 64) {
        float tt = 0.f;
#pragma unroll
        for (int i = 0; i < 8; ++i) tt += nrmp[((size_t)b * 8 + i) * K_ + k];
        const float n1 = sqrtf(tt);
        const float i1 = 1.f / fmaxf(n1, 1e-12f);
        inv1s[k] = i1;
        const float c2 = n1 * i1;
        col2[k] = c2 * c2;
    }
    __syncthreads();
    if (t == 0) {
        float tt = 0.f;
        for (int kk = 0; kk < 64; ++kk) tt += col2[kk];
        inv2p[0] = 1.f / fmaxf(sqrtf(tt), 1e-12f);
    }
    __syncthreads();
    const float i12 = inv1s[k] * inv2p[0];
#pragma unroll
    for (int j = 0; j < 8; ++j) {
        const int d = ds * 64 + dg + j * 8;
        out[(size_t)b * (D_ * K_) + (size_t)d * K_ + k] = vreg[j] * i12;
    }
}

// ---------------------------------------------------------------------------
extern "C" void kernel_launch(void* const* d_in, const int* in_sizes, int n_in,
                              void* d_out, int out_size, void* d_ws, size_t ws_size,
                              hipStream_t stream) {
    const float* X       = (const float*)d_in[0];  // [B, D, N]
    const float* W       = (const float*)d_in[1];  // [K, D]
    const float* bias    = (const float*)d_in[2];  // [K]
    const float* centers = (const float*)d_in[3];  // [D, K]
    float* out = (float*)d_out;

    char* ws = (char*)d_ws;
    const size_t aggBytes = (size_t)B_ * D_ * K_ * sizeof(float);   // 4 MB
    float*    aggs = (float*)ws;                              // 8 x 4 MB
    float*    ssp  = (float*)(ws + 8 * aggBytes);             // [B][8][4][K] = 256KB
    float*    nrmp = (float*)(ws + 8 * aggBytes + 262144);    // [B][8][K] = 64KB
    unsigned* cnt  = (unsigned*)(ws + 8 * aggBytes + 262144 + 65536);  // 2 counters

    hipMemsetAsync(cnt, 0, 128, stream);   // zero barrier counters each launch
    hipFuncSetAttribute((const void*)vlad_fused,
                        hipFuncAttributeMaxDynamicSharedMemorySize, SMEM_BYTES);

    vlad_fused<<<dim3(8, B_), 512, SMEM_BYTES, stream>>>(X, W, bias, centers,
                                                         aggs, ssp, nrmp, out, cnt);
}

// Round 13
// 84.975 us; speedup vs baseline: 1.4851x; 1.4851x over previous
//
#include <hip/hip_runtime.h>
#include <hip/hip_bf16.h>

#define B_ 32
#define D_ 512
#define K_ 64
#define N_ 4096

typedef __attribute__((ext_vector_type(8))) short short8;   // 8 bf16 (4 VGPRs)
typedef __attribute__((ext_vector_type(4))) short short4v;  // 4 bf16 (8 bytes)
typedef __attribute__((ext_vector_type(4))) float f32x4;

static __device__ __forceinline__ unsigned short f2bf(float f) {
    __hip_bfloat16 h = __float2bfloat16(f);
    return *reinterpret_cast<unsigned short*>(&h);
}
static __device__ __forceinline__ float bf2f(unsigned short u) {
    return __uint_as_float(((unsigned)u) << 16);
}

// LDS carve (bytes): WL 64K | XL 64K | XT 2x8K | PT 8K | sxc 1K
#define SMEM_BYTES 156672
#define WL_OFF 0
#define XL_OFF 65536
#define XT_OFF 131072
#define PT_OFF 147456
#define SXC_OFF 155648

// ---------------------------------------------------------------------------
// Fused kernel (R11 structure, best measured): pipe-diverse segments — per
// inter-barrier region {issue global load | f2bf+ds_write stage s+1 |
// ds_read+MFMA stage s}. X read from HBM exactly once; P never global.
// Softsum accumulated in registers. stage_write does ONE f2bf per element.
// Block 512 thr (8 waves), 1 block/CU. Grid 8 ns x 32 b.
// ---------------------------------------------------------------------------
__global__ __launch_bounds__(512, 2) void vlad_fused(const float* __restrict__ X,
                                                     const float* __restrict__ W,
                                                     const float* __restrict__ bias,
                                                     float* __restrict__ aggs,
                                                     float* __restrict__ ssp) {
    extern __shared__ char smem[];
    char* WLp = smem + WL_OFF;
    char* XLp = smem + XL_OFF;
    char* XTp = smem + XT_OFF;
    char* PTp = smem + PT_OFF;
    float2* sxc = (float2*)(smem + SXC_OFF);   // [8 waves][16 lr] (c, sum)

    const int ns = blockIdx.x;   // 0..7  (n-range [ns*512, ns*512+512))
    const int b  = blockIdx.y;
    const int t  = threadIdx.x;
    const int w  = t >> 6;
    const int l  = t & 63;
    const int lg = l >> 4;
    const int lr = l & 15;
    const int strip = w & 3;
    const int khalf = w >> 2;

    // staging role: 2 d-rows x 4 n-cols per thread
    const int dq2 = t >> 4;   // 0..31 -> local d0 = dq2*2
    const int nq  = t & 15;   // n0 = nq*4
    const float* Xbase = X + (size_t)b * D_ * N_ + ns * 512 + nq * 4;

    // ---- prefetch slots: stages 0..3 of tile 0 (slot = stage&3, static idx)
    float4 Sa[4], Sb[4];
#pragma unroll
    for (int s = 0; s < 4; ++s) {
        const float* Xs = Xbase + (size_t)(s * 64 + dq2 * 2) * N_;
        Sa[s] = *(const float4*)&Xs[0];
        Sb[s] = *(const float4*)&Xs[N_];
    }

    // ---- stage full W -> WL [64 k][512 d] bf16, 1KB rows, XOR-swz (validated)
#pragma unroll 4
    for (int j = 0; j < 16; ++j) {
        const int idx = t + j * 512;       // f4 index over [64 k][128 f4]
        const int k = idx >> 7;
        const int cf = idx & 127;
        const float4 wv = *(const float4*)&W[k * D_ + cf * 4];
        const int C = cf >> 1;
        const int swz = (C & ~7) | ((C ^ k) & 7);
        short4v pk;
        pk[0] = (short)f2bf(wv.x); pk[1] = (short)f2bf(wv.y);
        pk[2] = (short)f2bf(wv.z); pk[3] = (short)f2bf(wv.w);
        *(short4v*)(WLp + k * 1024 + (swz << 4) + (cf & 1) * 8) = pk;
    }

    float bias_r[2][4];
#pragma unroll
    for (int ktl = 0; ktl < 2; ++ktl)
#pragma unroll
        for (int r = 0; r < 4; ++r)
            bias_r[ktl][r] = bias[khalf * 32 + ktl * 16 + lg * 4 + r];

    f32x4 aacc[4][4];
#pragma unroll
    for (int m = 0; m < 4; ++m)
#pragma unroll
        for (int kt = 0; kt < 4; ++kt) {
            aacc[m][kt][0] = 0.f; aacc[m][kt][1] = 0.f;
            aacc[m][kt][2] = 0.f; aacc[m][kt][3] = 0.f;
        }
    float ssr[2][4];   // in-register softsum partials (this lane's 8 k's)
#pragma unroll
    for (int ktl = 0; ktl < 2; ++ktl)
#pragma unroll
        for (int r = 0; r < 4; ++r) ssr[ktl][r] = 0.f;

    // staged 2x4 block -> XL + XT[buf]; SINGLE f2bf per element (8 total)
    auto stage_write = [&](int buf, int dglob0, const float4& r0, const float4& r1) {
        const unsigned a0 = f2bf(r0.x), a1 = f2bf(r0.y), a2 = f2bf(r0.z), a3 = f2bf(r0.w);
        const unsigned b0 = f2bf(r1.x), b1 = f2bf(r1.y), b2 = f2bf(r1.z), b3 = f2bf(r1.w);
        // XL rows dglob0 / dglob0+1 (n-packed pairs)
        {
            const int d = dglob0;
            *(uint2*)(XLp + d * 128 + ((((nq >> 1) ^ d) & 7) << 4) + (nq & 1) * 8) =
                make_uint2(a0 | (a1 << 16), a2 | (a3 << 16));
        }
        {
            const int d = dglob0 + 1;
            *(uint2*)(XLp + d * 128 + ((((nq >> 1) ^ d) & 7) << 4) + (nq & 1) * 8) =
                make_uint2(b0 | (b1 << 16), b2 | (b3 << 16));
        }
        // XT (d-pair packed), conflict-free swizzle C^(n&7)^((n>>3)&7)
        const int C = dq2 >> 2;
        const unsigned xv[4] = {a0 | (b0 << 16), a1 | (b1 << 16),
                                a2 | (b2 << 16), a3 | (b3 << 16)};
#pragma unroll
        for (int c = 0; c < 4; ++c) {
            const int n = nq * 4 + c;
            const int sw = (C ^ (n & 7) ^ ((n >> 3) & 7)) & 7;
            *(unsigned*)(XTp + buf * 8192 + n * 128 + (sw << 4) + (dq2 & 3) * 4) = xv[c];
        }
    };

    __syncthreads();   // WL ready

    for (int nt = 0; nt < 8; ++nt) {
        const int base = nt * 8;

        // ---- tile prologue: write stage base (slot 0); refill slot0 <- base+4
        stage_write(0, 0 * 64 + dq2 * 2, Sa[0], Sb[0]);
        {
            const int s4 = base + 4;
            if (s4 < 64) {
                const int nt2 = s4 >> 3, d2 = s4 & 7;
                const float* Xs = Xbase + nt2 * 64 + (size_t)(d2 * 64 + dq2 * 2) * N_;
                Sa[0] = *(const float4*)&Xs[0];
                Sb[0] = *(const float4*)&Xs[N_];
            }
        }
        __syncthreads();

        f32x4 sacc[2];
#pragma unroll
        for (int ktl = 0; ktl < 2; ++ktl) {
            sacc[ktl][0] = 0.f; sacc[ktl][1] = 0.f; sacc[ktl][2] = 0.f; sacc[ktl][3] = 0.f;
        }

#pragma unroll
        for (int dsl = 0; dsl < 8; ++dsl) {
            const int cur = dsl & 1;
            if (dsl < 7) {
                // write NEXT stage into the other XT buf + its XL rows,
                // then refill that slot (loads stay in flight 4+ segments)
                const int slot = (dsl + 1) & 3;
                stage_write(cur ^ 1, (dsl + 1) * 64 + dq2 * 2, Sa[slot], Sb[slot]);
                const int s5 = base + dsl + 5;
                if (s5 < 64) {
                    const int nt2 = s5 >> 3, d2 = s5 & 7;
                    const float* Xs = Xbase + nt2 * 64 + (size_t)(d2 * 64 + dq2 * 2) * N_;
                    Sa[slot] = *(const float4*)&Xs[0];
                    Sb[slot] = *(const float4*)&Xs[N_];
                }
            }
            // MFMA scores stage dsl on XT buf[cur] (same inter-barrier region)
            const int n = strip * 16 + lr;
#pragma unroll
            for (int kc = 0; kc < 2; ++kc) {
                const int bC = kc * 4 + lg;
                const int sw = (bC ^ (n & 7) ^ ((n >> 3) & 7)) & 7;
                const short8 bfrag = *(const short8*)(XTp + cur * 8192 + n * 128 + (sw << 4));
#pragma unroll
                for (int ktl = 0; ktl < 2; ++ktl) {
                    const int k = khalf * 32 + ktl * 16 + lr;
                    const int aC = dsl * 8 + kc * 4 + lg;
                    const int swz = (aC & ~7) | ((aC ^ k) & 7);
                    const short8 afrag = *(const short8*)(WLp + k * 1024 + (swz << 4));
                    sacc[ktl] = __builtin_amdgcn_mfma_f32_16x16x32_bf16(afrag, bfrag, sacc[ktl], 0, 0, 0);
                }
            }
            if (dsl < 7) __syncthreads();
        }

        // ---- softmax over k: wave-local shift (exact), single (c,sum) exchange
        float p[2][4];
        float cw = -1e30f;
#pragma unroll
        for (int ktl = 0; ktl < 2; ++ktl)
#pragma unroll
            for (int r = 0; r < 4; ++r) {
                p[ktl][r] = sacc[ktl][r] + bias_r[ktl][r];
                cw = fmaxf(cw, p[ktl][r]);
            }
        cw = fmaxf(cw, __shfl_xor(cw, 16));
        cw = fmaxf(cw, __shfl_xor(cw, 32));
        float sum = 0.f;
#pragma unroll
        for (int ktl = 0; ktl < 2; ++ktl)
#pragma unroll
            for (int r = 0; r < 4; ++r) { p[ktl][r] = __expf(p[ktl][r] - cw); sum += p[ktl][r]; }
        sum += __shfl_xor(sum, 16);
        sum += __shfl_xor(sum, 32);
        if (l < 16) sxc[w * 16 + lr] = make_float2(cw, sum);
        __syncthreads();
        const float2 other = sxc[(w ^ 4) * 16 + lr];
        const float cstar = fmaxf(cw, other.x);
        const float e_own = __expf(cw - cstar);
        const float e_oth = __expf(other.x - cstar);
        const float scale = e_own / (sum * e_own + other.y * e_oth);

        // ---- P tile -> LDS [64 k][64 n] bf16 + in-register softsum partial
        {
            const int n = strip * 16 + lr;
#pragma unroll
            for (int ktl = 0; ktl < 2; ++ktl)
#pragma unroll
                for (int r = 0; r < 4; ++r) {
                    const int k = khalf * 32 + ktl * 16 + lg * 4 + r;
                    const unsigned short us = f2bf(p[ktl][r] * scale);
                    *(unsigned short*)(PTp + k * 128 + ((((n >> 3) ^ k) & 7) << 4) + (n & 7) * 2) = us;
                    ssr[ktl][r] += bf2f(us);   // bit-identical to a PT re-read
                }
        }
        __syncthreads();

        // ---- agg MFMA: contraction n=64 (2 steps); B-frags hoisted per kc
#pragma unroll
        for (int kc = 0; kc < 2; ++kc) {
            const int aC = kc * 4 + lg;
            short8 bfr[4];
#pragma unroll
            for (int kt = 0; kt < 4; ++kt) {
                const int kk2 = kt * 16 + lr;
                bfr[kt] = *(const short8*)(PTp + kk2 * 128 + (((aC ^ kk2) & 7) << 4));
            }
#pragma unroll
            for (int m = 0; m < 4; ++m) {
                const int d = w * 64 + m * 16 + lr;
                const short8 afrag = *(const short8*)(XLp + d * 128 + (((aC ^ d) & 7) << 4));
#pragma unroll
                for (int kt = 0; kt < 4; ++kt)
                    aacc[m][kt] = __builtin_amdgcn_mfma_f32_16x16x32_bf16(afrag, bfr[kt], aacc[m][kt], 0, 0, 0);
            }
        }
        __syncthreads();   // XL/PT reads done before next tile's prologue write
    }

    // ---- store agg partial: aggs[ns][b][d][k]
    float* ag = aggs + ((size_t)ns * B_ + b) * (D_ * K_);
#pragma unroll
    for (int m = 0; m < 4; ++m)
#pragma unroll
        for (int kt = 0; kt < 4; ++kt)
#pragma unroll
            for (int r = 0; r < 4; ++r)
                ag[(size_t)(w * 64 + m * 16 + lg * 4 + r) * K_ + kt * 16 + lr] = aacc[m][kt][r];

    // ---- softsum epilogue: butterfly over the 16-lane lr group, store partials
#pragma unroll
    for (int ktl = 0; ktl < 2; ++ktl)
#pragma unroll
        for (int r = 0; r < 4; ++r) {
            float v = ssr[ktl][r];
            v += __shfl_xor(v, 1);
            v += __shfl_xor(v, 2);
            v += __shfl_xor(v, 4);
            v += __shfl_xor(v, 8);
            ssr[ktl][r] = v;
        }
    if (lr == 0) {
#pragma unroll
        for (int ktl = 0; ktl < 2; ++ktl)
#pragma unroll
            for (int r = 0; r < 4; ++r) {
                const int k = khalf * 32 + ktl * 16 + lg * 4 + r;
                ssp[(((size_t)b * 8 + ns) * 4 + strip) * K_ + k] = ssr[ktl][r];
            }
    }
}

// ---------------------------------------------------------------------------
// Kernel D1: vsum = sum_ns aggs - centers*softsum -> aggsum; partial sumsq -> nrmp
// (ssp layout [b][8 ns][4 strip][64 k] = 32 partials per (b,k))
// ---------------------------------------------------------------------------
__global__ __launch_bounds__(256) void vlad_norm1(const float* __restrict__ aggs,
                                                  const float* __restrict__ centers,
                                                  const float* __restrict__ ssp,
                                                  float* __restrict__ aggsum,
                                                  float* __restrict__ nrmp) {
    const int ds = blockIdx.x;  // 0..7
    const int b  = blockIdx.y;
    const int t  = threadIdx.x;
    const int k  = t & 63;
    const int dg = t >> 6;

    __shared__ float red[4][64];

    float s0 = 0.f;
#pragma unroll
    for (int j = 0; j < 8; ++j)
        s0 += ssp[((size_t)b * 32 + dg * 8 + j) * K_ + k];
    red[dg][k] = s0;
    __syncthreads();
    const float s = red[0][k] + red[1][k] + red[2][k] + red[3][k];
    __syncthreads();

    float sq = 0.f;
    for (int d = ds * 64 + dg; d < ds * 64 + 64; d += 4) {
        float v = -centers[d * K_ + k] * s;
#pragma unroll
        for (int i = 0; i < 8; ++i)
            v += aggs[((size_t)i * B_ + b) * (D_ * K_) + (size_t)d * K_ + k];
        aggsum[((size_t)b * D_ + d) * K_ + k] = v;
        sq = fmaf(v, v, sq);
    }
    red[dg][k] = sq;
    __syncthreads();
    if (t < 64) nrmp[((size_t)b * 8 + ds) * K_ + k] =
        red[0][k] + red[1][k] + red[2][k] + red[3][k];
}

// ---------------------------------------------------------------------------
// Kernel D2: finalize norms (intra-D + global L2), scale aggsum -> out
// ---------------------------------------------------------------------------
__global__ __launch_bounds__(256) void vlad_norm2(const float* __restrict__ aggsum,
                                                  const float* __restrict__ nrmp,
                                                  float* __restrict__ out) {
    const int ds = blockIdx.x;  // 0..7
    const int b  = blockIdx.y;
    const int t  = threadIdx.x;
    const int k  = t & 63;
    const int dg = t >> 6;

    __shared__ float inv1s[64];
    __shared__ float col2[64];
    __shared__ float inv2s;

    if (t < 64) {
        float tt = 0.f;
#pragma unroll
        for (int i = 0; i < 8; ++i) tt += nrmp[((size_t)b * 8 + i) * K_ + k];
        const float n1 = sqrtf(tt);
        const float i1 = 1.f / fmaxf(n1, 1e-12f);
        inv1s[k] = i1;
        const float c2 = n1 * i1;
        col2[k] = c2 * c2;
    }
    __syncthreads();
    if (t == 0) {
        float tt = 0.f;
        for (int kk = 0; kk < 64; ++kk) tt += col2[kk];
        inv2s = 1.f / fmaxf(sqrtf(tt), 1e-12f);
    }
    __syncthreads();
    const float i12 = inv1s[k] * inv2s;
    for (int d = ds * 64 + dg; d < ds * 64 + 64; d += 4)
        out[(size_t)b * (D_ * K_) + (size_t)d * K_ + k] =
            aggsum[((size_t)b * D_ + d) * K_ + k] * i12;
}

// ---------------------------------------------------------------------------
extern "C" void kernel_launch(void* const* d_in, const int* in_sizes, int n_in,
                              void* d_out, int out_size, void* d_ws, size_t ws_size,
                              hipStream_t stream) {
    const float* X       = (const float*)d_in[0];  // [B, D, N]
    const float* W       = (const float*)d_in[1];  // [K, D]
    const float* bias    = (const float*)d_in[2];  // [K]
    const float* centers = (const float*)d_in[3];  // [D, K]
    float* out = (float*)d_out;

    char* ws = (char*)d_ws;
    const size_t aggBytes = (size_t)B_ * D_ * K_ * sizeof(float);   // 4 MB
    float* aggs   = (float*)ws;                               // 8 x 4 MB
    float* aggsum = (float*)(ws + 8 * aggBytes);              // 4 MB
    float* ssp    = (float*)(ws + 9 * aggBytes);              // [B][8][4][K] = 256KB
    float* nrmp   = (float*)(ws + 9 * aggBytes + 262144);     // [B][8][K]

    hipFuncSetAttribute((const void*)vlad_fused,
                        hipFuncAttributeMaxDynamicSharedMemorySize, SMEM_BYTES);

    vlad_fused<<<dim3(8, B_), 512, SMEM_BYTES, stream>>>(X, W, bias, aggs, ssp);
    vlad_norm1<<<dim3(8, B_), 256, 0, stream>>>(aggs, centers, ssp, aggsum, nrmp);
    vlad_norm2<<<dim3(8, B_), 256, 0, stream>>>(aggsum, nrmp, out);
}